// Round 2
// baseline (1434.286 us; speedup 1.0000x reference)
//
#include <hip/hip_runtime.h>
#include <hip/hip_bf16.h>

#define EMB 128
#define NRBF 6

// ---------------------------------------------------------------------------
// Stage 1: per-edge  prod = (e_rbf @ W_edge) * m_ji, scatter-add to acc[dst].
// 32 lanes per edge, 4 channels (float4) per lane. Grid-stride over edges.
// W_edge columns held in registers (24 floats/lane), amortized over ~37 edges.
// ---------------------------------------------------------------------------
__global__ __launch_bounds__(256) void edge_scatter_kernel(
    const float* __restrict__ m_ji,
    const float* __restrict__ e_rbf,
    const int*   __restrict__ nbr,
    const float* __restrict__ W_edge,
    float* __restrict__ acc,
    int E, int num_slots)
{
    const int gtid = blockIdx.x * 256 + threadIdx.x;
    const int slot = gtid >> 5;
    const int lane = gtid & 31;
    const int c    = lane * 4;

    float4 wc[NRBF];
#pragma unroll
    for (int k = 0; k < NRBF; ++k)
        wc[k] = *reinterpret_cast<const float4*>(&W_edge[k * EMB + c]);

    for (int e = slot; e < E; e += num_slots) {
        float r[NRBF];
#pragma unroll
        for (int k = 0; k < NRBF; ++k) r[k] = e_rbf[e * NRBF + k];

        float4 w = make_float4(0.f, 0.f, 0.f, 0.f);
#pragma unroll
        for (int k = 0; k < NRBF; ++k) {
            w.x += r[k] * wc[k].x;
            w.y += r[k] * wc[k].y;
            w.z += r[k] * wc[k].z;
            w.w += r[k] * wc[k].w;
        }

        const float4 m = *reinterpret_cast<const float4*>(&m_ji[(size_t)e * EMB + c]);
        const int dst = nbr[e * 2 + 1];
        float* p = acc + (size_t)dst * EMB + c;
        unsafeAtomicAdd(p + 0, w.x * m.x);
        unsafeAtomicAdd(p + 1, w.y * m.y);
        unsafeAtomicAdd(p + 2, w.z * m.z);
        unsafeAtomicAdd(p + 3, w.w * m.w);
    }
}

// ---------------------------------------------------------------------------
// Stage 2: one dense layer  out = act(in @ W + b), rows independent -> safe
// in-place (block stages its own 64 rows into LDS before writing them back).
// 512 threads: 16 row-groups x 32 col-groups; 4x4 register tile per thread.
// W in LDS (64 KB, linear). Input tile transposed in LDS, row length padded
// to 68 (keeps 16B alignment for float4 reads, breaks staging write stride).
// Inner loop: 2x ds_read_b128 + 16 FMA per k  -> FMA-bound.
// ---------------------------------------------------------------------------
template<bool ACT, bool HASB>
__global__ __launch_bounds__(512) void mlp_layer_kernel(
    const float* __restrict__ in,
    const float* __restrict__ W,
    const float* __restrict__ bias,
    float* __restrict__ out, int NA)
{
    __shared__ __align__(16) float sW[EMB * EMB];
    __shared__ __align__(16) float sIn[EMB][68];

    const int tid = threadIdx.x;
    const int r0  = blockIdx.x * 64;

    // stage W (linear copy, coalesced, conflict-free)
    for (int i = tid * 4; i < EMB * EMB; i += 512 * 4)
        *reinterpret_cast<float4*>(&sW[i]) = *reinterpret_cast<const float4*>(&W[i]);

    // stage input tile transposed: sIn[col][row]
    for (int idx = tid; idx < 64 * 32; idx += 512) {
        const int row = idx >> 5;   // 0..63
        const int cg  = idx & 31;   // col group
        const int grow = r0 + row;
        float4 v = make_float4(0.f, 0.f, 0.f, 0.f);
        if (grow < NA)
            v = *reinterpret_cast<const float4*>(&in[(size_t)grow * EMB + cg * 4]);
        sIn[cg * 4 + 0][row] = v.x;
        sIn[cg * 4 + 1][row] = v.y;
        sIn[cg * 4 + 2][row] = v.z;
        sIn[cg * 4 + 3][row] = v.w;
    }
    __syncthreads();

    const int rg = tid >> 5;   // 0..15 -> rows rg*4 .. rg*4+3
    const int cg = tid & 31;   // 0..31 -> cols cg*4 .. cg*4+3

    float acc[4][4];
#pragma unroll
    for (int r = 0; r < 4; ++r)
#pragma unroll
        for (int j = 0; j < 4; ++j) acc[r][j] = 0.f;

#pragma unroll 8
    for (int k = 0; k < EMB; ++k) {
        const float4 w = *reinterpret_cast<const float4*>(&sW[k * EMB + cg * 4]);
        const float4 x = *reinterpret_cast<const float4*>(&sIn[k][rg * 4]);
        acc[0][0] += x.x * w.x; acc[0][1] += x.x * w.y; acc[0][2] += x.x * w.z; acc[0][3] += x.x * w.w;
        acc[1][0] += x.y * w.x; acc[1][1] += x.y * w.y; acc[1][2] += x.y * w.z; acc[1][3] += x.y * w.w;
        acc[2][0] += x.z * w.x; acc[2][1] += x.z * w.y; acc[2][2] += x.z * w.z; acc[2][3] += x.z * w.w;
        acc[3][0] += x.w * w.x; acc[3][1] += x.w * w.y; acc[3][2] += x.w * w.z; acc[3][3] += x.w * w.w;
    }

    float4 bv = make_float4(0.f, 0.f, 0.f, 0.f);
    if (HASB)
        bv = *reinterpret_cast<const float4*>(&bias[cg * 4]);

#pragma unroll
    for (int r = 0; r < 4; ++r) {
        const int grow = r0 + rg * 4 + r;
        if (grow < NA) {
            float4 o;
            o.x = acc[r][0] + bv.x;
            o.y = acc[r][1] + bv.y;
            o.z = acc[r][2] + bv.z;
            o.w = acc[r][3] + bv.w;
            if (ACT) {
                o.x *= 1.f / (1.f + __expf(-o.x));
                o.y *= 1.f / (1.f + __expf(-o.y));
                o.z *= 1.f / (1.f + __expf(-o.z));
                o.w *= 1.f / (1.f + __expf(-o.w));
            }
            *reinterpret_cast<float4*>(&out[(size_t)grow * EMB + cg * 4]) = o;
        }
    }
}

extern "C" void kernel_launch(void* const* d_in, const int* in_sizes, int n_in,
                              void* d_out, int out_size, void* d_ws, size_t ws_size,
                              hipStream_t stream) {
    const float* m_ji   = (const float*)d_in[0];
    const float* e_rbf  = (const float*)d_in[1];
    const int*   nbr    = (const int*)d_in[2];
    // d_in[3] = num_atoms scalar (we derive NA from out_size instead)
    const float* W_edge = (const float*)d_in[4];
    const float* W1     = (const float*)d_in[5];
    const float* b1     = (const float*)d_in[6];
    const float* W2     = (const float*)d_in[7];
    const float* b2     = (const float*)d_in[8];
    const float* W3     = (const float*)d_in[9];
    const float* b3     = (const float*)d_in[10];
    const float* W4     = (const float*)d_in[11];

    float* out = (float*)d_out;
    float* acc = (float*)d_ws;

    const int E  = in_sizes[0] / EMB;     // 600000
    const int NA = out_size / EMB;        // 20000

    // zero the node accumulator (ws is re-poisoned to 0xAA before every call)
    hipMemsetAsync(d_ws, 0, (size_t)NA * EMB * sizeof(float), stream);

    const int EBLK = 2048;
    edge_scatter_kernel<<<EBLK, 256, 0, stream>>>(m_ji, e_rbf, nbr, W_edge, acc,
                                                  E, EBLK * 256 / 32);

    const int nb = (NA + 63) / 64;
    mlp_layer_kernel<true,  true ><<<nb, 512, 0, stream>>>(acc, W1, b1,      out, NA);
    mlp_layer_kernel<true,  true ><<<nb, 512, 0, stream>>>(out, W2, b2,      out, NA);
    mlp_layer_kernel<true,  true ><<<nb, 512, 0, stream>>>(out, W3, b3,      out, NA);
    mlp_layer_kernel<false, false><<<nb, 512, 0, stream>>>(out, W4, nullptr, out, NA);
}

// Round 5
// 668.466 us; speedup vs baseline: 2.1456x; 2.1456x over previous
//
#include <hip/hip_runtime.h>
#include <hip/hip_bf16.h>

#define EMB 128
#define NRBF 6

// ============================================================================
// CSR-gather pipeline for segment_sum (replaces float atomics: round-2 rocprof
// showed WRITE_SIZE=1.2GB = 76.8M atomics x 16B RMW, atomic-unit-bound at 17%
// HBM / 1.9% VALU). CSR build = 1.2M int atomics, then atomic-free gather.
// ============================================================================

__global__ __launch_bounds__(256) void hist_kernel(
    const int* __restrict__ nbr, int* __restrict__ counts, int E)
{
    const int e = blockIdx.x * 256 + threadIdx.x;
    if (e < E) atomicAdd(&counts[nbr[e * 2 + 1]], 1);
}

// single block, 1024 threads: exclusive scan of counts[NA] -> offsets, cursor
__global__ __launch_bounds__(1024) void scan_kernel(
    const int* __restrict__ counts, int* __restrict__ offsets,
    int* __restrict__ cursor, int NA)
{
    __shared__ int part[1024];
    const int tid = threadIdx.x;
    const int CH  = (NA + 1023) / 1024;
    const int base = tid * CH;

    int s = 0;
    for (int i = 0; i < CH; ++i) {
        int idx = base + i;
        if (idx < NA) s += counts[idx];
    }
    part[tid] = s;
    __syncthreads();

    // Hillis-Steele inclusive scan (reads complete before barrier, then write)
    for (int d = 1; d < 1024; d <<= 1) {
        int v   = part[tid];
        int add = (tid >= d) ? part[tid - d] : 0;
        __syncthreads();
        part[tid] = v + add;
        __syncthreads();
    }

    int excl = (tid == 0) ? 0 : part[tid - 1];
    for (int i = 0; i < CH; ++i) {
        int idx = base + i;
        if (idx < NA) {
            offsets[idx] = excl;
            cursor[idx]  = excl;
            excl += counts[idx];
        }
    }
    if (tid == 1023) offsets[NA] = excl;   // == E
}

__global__ __launch_bounds__(256) void scatter_kernel(
    const int* __restrict__ nbr, int* __restrict__ cursor,
    int* __restrict__ perm, int E)
{
    const int e = blockIdx.x * 256 + threadIdx.x;
    if (e < E) {
        const int dst = nbr[e * 2 + 1];
        const int pos = atomicAdd(&cursor[dst], 1);
        perm[pos] = e;
    }
}

// one 32-lane group per atom: sum_{e in atom} (e_rbf[e] @ W_edge) * m_ji[e]
// -> acc[atom] written once, no atomics. Row loads are 512B contiguous.
__global__ __launch_bounds__(256) void gather_kernel(
    const float* __restrict__ m_ji,
    const float* __restrict__ e_rbf,
    const float* __restrict__ W_edge,
    const int*   __restrict__ offsets,
    const int*   __restrict__ perm,
    float* __restrict__ acc, int NA)
{
    const int g    = (blockIdx.x * 256 + threadIdx.x) >> 5;
    const int lane = threadIdx.x & 31;
    if (g >= NA) return;
    const int c = lane * 4;

    float4 wc[NRBF];
#pragma unroll
    for (int k = 0; k < NRBF; ++k)
        wc[k] = *reinterpret_cast<const float4*>(&W_edge[k * EMB + c]);

    const int p0 = offsets[g];
    const int p1 = offsets[g + 1];

    float4 racc = make_float4(0.f, 0.f, 0.f, 0.f);
    for (int p = p0; p < p1; ++p) {
        const int e = perm[p];
        float r[NRBF];
#pragma unroll
        for (int k = 0; k < NRBF; ++k) r[k] = e_rbf[e * NRBF + k];

        float4 w = make_float4(0.f, 0.f, 0.f, 0.f);
#pragma unroll
        for (int k = 0; k < NRBF; ++k) {
            w.x += r[k] * wc[k].x;
            w.y += r[k] * wc[k].y;
            w.z += r[k] * wc[k].z;
            w.w += r[k] * wc[k].w;
        }
        const float4 m = *reinterpret_cast<const float4*>(&m_ji[(size_t)e * EMB + c]);
        racc.x += w.x * m.x;
        racc.y += w.y * m.y;
        racc.z += w.z * m.z;
        racc.w += w.w * m.w;
    }
    *reinterpret_cast<float4*>(&acc[(size_t)g * EMB + c]) = racc;
}

// ---------------------------------------------------------------------------
// Fallback (ws too small): round-2 atomic scatter. Known-correct, slow.
// ---------------------------------------------------------------------------
__global__ __launch_bounds__(256) void edge_scatter_kernel(
    const float* __restrict__ m_ji,
    const float* __restrict__ e_rbf,
    const int*   __restrict__ nbr,
    const float* __restrict__ W_edge,
    float* __restrict__ acc,
    int E, int num_slots)
{
    const int gtid = blockIdx.x * 256 + threadIdx.x;
    const int slot = gtid >> 5;
    const int lane = gtid & 31;
    const int c    = lane * 4;

    float4 wc[NRBF];
#pragma unroll
    for (int k = 0; k < NRBF; ++k)
        wc[k] = *reinterpret_cast<const float4*>(&W_edge[k * EMB + c]);

    for (int e = slot; e < E; e += num_slots) {
        float r[NRBF];
#pragma unroll
        for (int k = 0; k < NRBF; ++k) r[k] = e_rbf[e * NRBF + k];
        float4 w = make_float4(0.f, 0.f, 0.f, 0.f);
#pragma unroll
        for (int k = 0; k < NRBF; ++k) {
            w.x += r[k] * wc[k].x;
            w.y += r[k] * wc[k].y;
            w.z += r[k] * wc[k].z;
            w.w += r[k] * wc[k].w;
        }
        const float4 m = *reinterpret_cast<const float4*>(&m_ji[(size_t)e * EMB + c]);
        const int dst = nbr[e * 2 + 1];
        float* p = acc + (size_t)dst * EMB + c;
        unsafeAtomicAdd(p + 0, w.x * m.x);
        unsafeAtomicAdd(p + 1, w.y * m.y);
        unsafeAtomicAdd(p + 2, w.z * m.z);
        unsafeAtomicAdd(p + 3, w.w * m.w);
    }
}

// ---------------------------------------------------------------------------
// Dense layer out = act(in @ W + b) — unchanged from round 2 (no dispatch-level
// timing evidence on it yet; it will show in top-5 once gather lands).
// ---------------------------------------------------------------------------
template<bool ACT, bool HASB>
__global__ __launch_bounds__(512) void mlp_layer_kernel(
    const float* __restrict__ in,
    const float* __restrict__ W,
    const float* __restrict__ bias,
    float* __restrict__ out, int NA)
{
    __shared__ __align__(16) float sW[EMB * EMB];
    __shared__ __align__(16) float sIn[EMB][68];

    const int tid = threadIdx.x;
    const int r0  = blockIdx.x * 64;

    for (int i = tid * 4; i < EMB * EMB; i += 512 * 4)
        *reinterpret_cast<float4*>(&sW[i]) = *reinterpret_cast<const float4*>(&W[i]);

    for (int idx = tid; idx < 64 * 32; idx += 512) {
        const int row = idx >> 5;
        const int cg  = idx & 31;
        const int grow = r0 + row;
        float4 v = make_float4(0.f, 0.f, 0.f, 0.f);
        if (grow < NA)
            v = *reinterpret_cast<const float4*>(&in[(size_t)grow * EMB + cg * 4]);
        sIn[cg * 4 + 0][row] = v.x;
        sIn[cg * 4 + 1][row] = v.y;
        sIn[cg * 4 + 2][row] = v.z;
        sIn[cg * 4 + 3][row] = v.w;
    }
    __syncthreads();

    const int rg = tid >> 5;
    const int cg = tid & 31;

    float acc[4][4];
#pragma unroll
    for (int r = 0; r < 4; ++r)
#pragma unroll
        for (int j = 0; j < 4; ++j) acc[r][j] = 0.f;

#pragma unroll 8
    for (int k = 0; k < EMB; ++k) {
        const float4 w = *reinterpret_cast<const float4*>(&sW[k * EMB + cg * 4]);
        const float4 x = *reinterpret_cast<const float4*>(&sIn[k][rg * 4]);
        acc[0][0] += x.x * w.x; acc[0][1] += x.x * w.y; acc[0][2] += x.x * w.z; acc[0][3] += x.x * w.w;
        acc[1][0] += x.y * w.x; acc[1][1] += x.y * w.y; acc[1][2] += x.y * w.z; acc[1][3] += x.y * w.w;
        acc[2][0] += x.z * w.x; acc[2][1] += x.z * w.y; acc[2][2] += x.z * w.z; acc[2][3] += x.z * w.w;
        acc[3][0] += x.w * w.x; acc[3][1] += x.w * w.y; acc[3][2] += x.w * w.z; acc[3][3] += x.w * w.w;
    }

    float4 bv = make_float4(0.f, 0.f, 0.f, 0.f);
    if (HASB)
        bv = *reinterpret_cast<const float4*>(&bias[cg * 4]);

#pragma unroll
    for (int r = 0; r < 4; ++r) {
        const int grow = r0 + rg * 4 + r;
        if (grow < NA) {
            float4 o;
            o.x = acc[r][0] + bv.x;
            o.y = acc[r][1] + bv.y;
            o.z = acc[r][2] + bv.z;
            o.w = acc[r][3] + bv.w;
            if (ACT) {
                o.x *= 1.f / (1.f + __expf(-o.x));
                o.y *= 1.f / (1.f + __expf(-o.y));
                o.z *= 1.f / (1.f + __expf(-o.z));
                o.w *= 1.f / (1.f + __expf(-o.w));
            }
            *reinterpret_cast<float4*>(&out[(size_t)grow * EMB + cg * 4]) = o;
        }
    }
}

extern "C" void kernel_launch(void* const* d_in, const int* in_sizes, int n_in,
                              void* d_out, int out_size, void* d_ws, size_t ws_size,
                              hipStream_t stream) {
    const float* m_ji   = (const float*)d_in[0];
    const float* e_rbf  = (const float*)d_in[1];
    const int*   nbr    = (const int*)d_in[2];
    const float* W_edge = (const float*)d_in[4];
    const float* W1     = (const float*)d_in[5];
    const float* b1     = (const float*)d_in[6];
    const float* W2     = (const float*)d_in[7];
    const float* b2     = (const float*)d_in[8];
    const float* W3     = (const float*)d_in[9];
    const float* b3     = (const float*)d_in[10];
    const float* W4     = (const float*)d_in[11];

    float* out = (float*)d_out;

    const int E  = in_sizes[0] / EMB;     // 600000
    const int NA = out_size / EMB;        // 20000

    // ws layout (256B-aligned regions)
    char* w = (char*)d_ws;
    size_t off = 0;
    auto take = [&](size_t bytes) {
        char* p = w + off;
        off = (off + bytes + 255) & ~(size_t)255;
        return p;
    };
    float* acc     = (float*)take((size_t)NA * EMB * sizeof(float));
    int*   counts  = (int*)  take((size_t)NA * sizeof(int));
    int*   offsets = (int*)  take((size_t)(NA + 1) * sizeof(int));
    int*   cursor  = (int*)  take((size_t)NA * sizeof(int));
    int*   perm    = (int*)  take((size_t)E * sizeof(int));
    const bool csr_ok = off <= ws_size;

    if (csr_ok) {
        hipMemsetAsync(counts, 0, (size_t)NA * sizeof(int), stream);
        const int eb = (E + 255) / 256;
        hist_kernel   <<<eb, 256, 0, stream>>>(nbr, counts, E);
        scan_kernel   <<<1, 1024, 0, stream>>>(counts, offsets, cursor, NA);
        scatter_kernel<<<eb, 256, 0, stream>>>(nbr, cursor, perm, E);
        const int gb = (NA * 32 + 255) / 256;
        gather_kernel <<<gb, 256, 0, stream>>>(m_ji, e_rbf, W_edge, offsets, perm, acc, NA);
    } else {
        hipMemsetAsync(acc, 0, (size_t)NA * EMB * sizeof(float), stream);
        const int EBLK = 2048;
        edge_scatter_kernel<<<EBLK, 256, 0, stream>>>(m_ji, e_rbf, nbr, W_edge, acc,
                                                      E, EBLK * 256 / 32);
    }

    const int nb = (NA + 63) / 64;
    mlp_layer_kernel<true,  true ><<<nb, 512, 0, stream>>>(acc, W1, b1,      out, NA);
    mlp_layer_kernel<true,  true ><<<nb, 512, 0, stream>>>(out, W2, b2,      out, NA);
    mlp_layer_kernel<true,  true ><<<nb, 512, 0, stream>>>(out, W3, b3,      out, NA);
    mlp_layer_kernel<false, false><<<nb, 512, 0, stream>>>(out, W4, nullptr, out, NA);
}